// Round 16
// baseline (11696.295 us; speedup 1.0000x reference)
//
#include <hip/hip_runtime.h>
#include <hip/hip_bf16.h>
#include <math.h>

#define SEQL   4096
#define NITEMS 512
#define HID    256
#define NLAY   16
#define QS     64      // ring slots = 8 chunks x 8 steps
#define CHUNK  8
#define NCHUNK (SEQL / CHUNK)
#define TPB    4

typedef float f4 __attribute__((ext_vector_type(4)));
typedef short short8 __attribute__((ext_vector_type(8)));
typedef unsigned short u16x4 __attribute__((ext_vector_type(4)));

// Workspace layout (float offsets)
#define P_OFF   ((size_t)0)                               // P[4][SEQL][HID]
#define H_OFF   (P_OFF + (size_t)4*SEQL*HID)              // Hring[4][NLAY][QS][HID]
#define AP_OFF  (H_OFF + (size_t)4*NLAY*QS*HID)           // Apart[4][NLAY][QS][HID]
#define HF_OFF  (AP_OFF + (size_t)4*NLAY*QS*HID)          // hfinal[4][HID]
#define FLAG_OFF_FLOATS (HF_OFF + (size_t)1024)
#define NFLAGS 256

// ---------------------------------------------------------------------------
__device__ __forceinline__ float ld_coh_b32(const float* p) {
    float r;
    asm volatile("global_load_dword %0, %1, off sc0 sc1" : "=v"(r) : "v"(p));
    return r;
}
__device__ __forceinline__ void st_coh_f4(float* p, f4 v) {
    asm volatile("global_store_dwordx4 %0, %1, off sc0 sc1" :: "v"(p), "v"(v) : "memory");
}
__device__ __forceinline__ void st_coh_u32(unsigned* p, unsigned v) {
    asm volatile("global_store_dword %0, %1, off sc0 sc1" :: "v"(p), "v"(v) : "memory");
}
__device__ __forceinline__ unsigned uload(const unsigned* p) {
    return __hip_atomic_load(p, __ATOMIC_RELAXED, __HIP_MEMORY_SCOPE_AGENT);
}

#define SBAR()  { __builtin_amdgcn_s_barrier(); __builtin_amdgcn_sched_barrier(0); }
#define LGKM0() { asm volatile("s_waitcnt lgkmcnt(0)" ::: "memory"); __builtin_amdgcn_sched_barrier(0); }
#define VMW0()  { asm volatile("s_waitcnt vmcnt(0)" ::: "memory"); __builtin_amdgcn_sched_barrier(0); }

__device__ __forceinline__ void spin_ge(const unsigned* p, unsigned target, bool* dead) {
    if (*dead) return;
    unsigned it = 0;
    while (uload(p) < target) {
        __builtin_amdgcn_s_sleep(1);
        if (++it > (1u << 20)) { *dead = true; break; }
    }
}

__device__ __forceinline__ float tanh_fast(float x) {
    return 1.f - __fdividef(2.f, __expf(2.f * x) + 1.f);
}

// bf16 split helpers (RNE)
__device__ __forceinline__ unsigned short bf_hi(float f) {
    unsigned u = __float_as_uint(f);
    return (unsigned short)((u + 0x7FFFu + ((u >> 16) & 1u)) >> 16);
}
__device__ __forceinline__ float bf2f(unsigned short s) {
    return __uint_as_float(((unsigned)s) << 16);
}

// ---------------------------------------------------------------------------
// Kernel 1: input projection P[c][t][j] = sum_k Wih0_c[j,k] * x[t,k,c]
__global__ __launch_bounds__(1024) void proj_kernel(
    const float* __restrict__ x, const float* __restrict__ Wlp,
    const float* __restrict__ Wlpv, float* __restrict__ P)
{
    __shared__ float xs[TPB][4][NITEMS];
    const int tid = threadIdx.x;
    const int t0 = blockIdx.x * TPB;

    #pragma unroll
    for (int tt = 0; tt < TPB; ++tt) {
        const float2* src = (const float2*)(x + (size_t)(t0 + tt) * NITEMS * 4);
        float2 v = src[tid];
        int e = 2 * tid;
        xs[tt][e & 3][e >> 2]       = v.x;
        xs[tt][(e + 1) & 3][e >> 2] = v.y;
    }
    __syncthreads();

    const int c = tid >> 8, j = tid & 255;
    const float* W = (c == 1) ? Wlpv : Wlp;
    const float4* row = (const float4*)(W + (size_t)j * NITEMS);
    float acc[TPB] = {0.f, 0.f, 0.f, 0.f};
    #pragma unroll 4
    for (int k4 = 0; k4 < NITEMS / 4; ++k4) {
        float4 w = row[k4];
        #pragma unroll
        for (int tt = 0; tt < TPB; ++tt) {
            float4 xv = *(const float4*)(&xs[tt][c][k4 * 4]);
            acc[tt] = fmaf(w.x, xv.x, fmaf(w.y, xv.y, fmaf(w.z, xv.z, fmaf(w.w, xv.w, acc[tt]))));
        }
    }
    #pragma unroll
    for (int tt = 0; tt < TPB; ++tt)
        P[((size_t)c * SEQL + (t0 + tt)) * HID + j] = acc[tt];
}

// ---------------------------------------------------------------------------
// Kernel 2: layer-pipelined RNN, MFMA core (bf16 3-term split, f32-grade).
// 124 blocks x 256 threads (4 waves). Wave w owns rows 64w..64w+63 (4 row-
// tiles of 16). A-frag (weights) resident in VGPRs; h as bf16 hi/lo images
// in LDS. Chunked flag protocol (R12 semantics), wave-private polls.
__global__ __launch_bounds__(256, 1) void rnn_pipe(
    const float* __restrict__ lp_Wih,  const float* __restrict__ lp_Whh,
    const float* __restrict__ lp_bih,  const float* __restrict__ lp_bhh,
    const float* __restrict__ lpv_Wih, const float* __restrict__ lpv_Whh,
    const float* __restrict__ lpv_bih, const float* __restrict__ lpv_bhh,
    const float* __restrict__ P, float* __restrict__ Hring,
    float* __restrict__ Apart, float* __restrict__ hfinal,
    unsigned* __restrict__ Hflag, unsigned* __restrict__ Aflag)
{
    __shared__ __align__(16) unsigned short img_hi[2][HID], img_lo[2][HID]; // B: h images
    __shared__ __align__(16) unsigned short stgH[CHUNK][HID], stgL[CHUNK][HID]; // A: staged h
    __shared__ __align__(16) float apL[CHUNK][HID];                         // B: inputs+bias

    const int b = blockIdx.x;
    if (b >= 124) return;
    const int tid = threadIdx.x;

    const int c = b / 31;
    const int r = b % 31;
    const int role = (r < NLAY) ? 0 : 1;
    const int l = (r < NLAY) ? r : (r - NLAY + 1);

    const float* Wih = (c == 1) ? lpv_Wih : lp_Wih;
    const float* Whh = (c == 1) ? lpv_Whh : lp_Whh;
    const float* bih = (c == 1) ? lpv_bih : lp_bih;
    const float* bhh = (c == 1) ? lpv_bhh : lp_bhh;

    const int wv   = tid >> 6;       // wave 0..3
    const int lane = tid & 63;
    const int g    = lane >> 4;      // k-group 0..3
    const int col  = lane & 15;      // MFMA m (A-rows) / n (B-cols)
    const int m    = tid;            // staging row 0..255
    bool dead = false;

    // ---- preload A-fragments: wa[t][kt] covers rows 16*(4wv+t).. , k 32kt.. ----
    // Assumed layout (consistent A/B => k-permutation cancels):
    //   A[row][k]: row = 16*RT + col, k = 32*kt + 8*g + r
    short8 waH[4][8], waL[4][8];
    {
        const float* Wb = (role == 0) ? (Whh + (size_t)l * HID * HID)
                                      : (Wih + (size_t)(l - 1) * HID * HID);
        #pragma unroll
        for (int t = 0; t < 4; ++t) {
            #pragma unroll
            for (int kt = 0; kt < 8; ++kt) {
                const float* p = Wb + (size_t)(16 * (4 * wv + t) + col) * HID + 32 * kt + 8 * g;
                f4 v0 = *(const f4*)p;
                f4 v1 = *(const f4*)(p + 4);
                float vv[8] = {v0.x, v0.y, v0.z, v0.w, v1.x, v1.y, v1.z, v1.w};
                short8 hi8, lo8;
                #pragma unroll
                for (int jj = 0; jj < 8; ++jj) {
                    unsigned short h_ = bf_hi(vv[jj]);
                    hi8[jj] = (short)h_;
                    lo8[jj] = (short)bf_hi(vv[jj] - bf2f(h_));
                }
                waH[t][kt] = hi8; waL[t][kt] = lo8;
            }
        }
    }
    #pragma unroll
    for (int t = 0; t < 4; ++t) {
        #pragma unroll
        for (int kt = 0; kt < 8; ++kt)
            asm volatile("" : "+v"(waH[t][kt]), "+v"(waL[t][kt]));
    }

    if (role == 0) {
        // ===================== B role =====================
        const bool l0 = (l == 0);
        const float*    Psrc  = P + (size_t)c * SEQL * HID;
        const float*    apbuf = Apart + ((size_t)(c * NLAY + l) * QS) * HID;
        const unsigned* af    = Aflag + c * NLAY + l;
        unsigned*       myHfl = Hflag + c * NLAY + l;
        const unsigned* consA = Aflag + c * NLAY + l + 1;   // valid when l<15
        float*          Hout  = Hring + ((size_t)(c * NLAY + l) * QS) * HID;
        float*          hfin  = hfinal + (size_t)c * HID;
        const float bias_m = bih[l * HID + m] + bhh[l * HID + m];

        img_hi[0][m] = 0; img_lo[0][m] = 0;   // h(-1) = 0

        float apn[CHUNK];
        bool havePF = false, bpok = true;

        for (int k = 0; k < NCHUNK; ++k) {
            // ---------- chunk top ----------
            if (lane == 0) {
                if (!l0 && !havePF) spin_ge(af, (unsigned)(k + 1), &dead);
                if (l < NLAY - 1 && k >= CHUNK && !bpok) spin_ge(consA, (unsigned)(k - 7), &dead);
            }
            unsigned afv = 0u, bpv = 0u;
            const bool pollIn = (!l0) && (k + 1 < NCHUNK);
            const bool pollBp = (l < NLAY - 1) && (k + 1 >= CHUNK) && (k + 1 < NCHUNK);
            if (lane == 0 && pollIn)
                asm volatile("global_load_dword %0, %1, off sc0 sc1" : "=v"(afv) : "v"(af));
            if (lane == 0 && pollBp)
                asm volatile("global_load_dword %0, %1, off sc0 sc1" : "=v"(bpv) : "v"(consA));

            float ap8[CHUNK];
            if (havePF) {
                VMW0();
                #pragma unroll
                for (int s = 0; s < CHUNK; ++s) ap8[s] = apn[s] + bias_m;
            } else {
                if (l0) {
                    #pragma unroll
                    for (int s = 0; s < CHUNK; ++s)
                        ap8[s] = Psrc[(size_t)(CHUNK * k + s) * HID + m];
                    VMW0();
                } else {
                    #pragma unroll
                    for (int s = 0; s < CHUNK; ++s)
                        ap8[s] = ld_coh_b32(apbuf + (size_t)((k & 7) * CHUNK + s) * HID + m);
                    VMW0();
                }
                #pragma unroll
                for (int s = 0; s < CHUNK; ++s) ap8[s] += bias_m;
            }
            {   // wave-uniform gate values (polls drained by VMW0 above)
                unsigned afs = (unsigned)__builtin_amdgcn_readfirstlane((int)afv);
                unsigned bps = (unsigned)__builtin_amdgcn_readfirstlane((int)bpv);
                havePF = pollIn ? (afs >= (unsigned)(k + 2)) : (l0 && (k + 1 < NCHUNK));
                bpok   = pollBp ? (bps >= (unsigned)(k - 6)) : true;
            }
            #pragma unroll
            for (int s = 0; s < CHUNK; ++s) apL[s][m] = ap8[s];
            LGKM0(); SBAR();

            // ---------- 8 inner steps (one barrier each) ----------
            for (int s = 0; s < CHUNK; ++s) {
                const int p = s & 1;
                f4 accA[4], accB[4], accC[4];
                #pragma unroll
                for (int t = 0; t < 4; ++t) { accA[t] = (f4)0.f; accB[t] = (f4)0.f; accC[t] = (f4)0.f; }
                #pragma unroll
                for (int kt = 0; kt < 8; ++kt) {
                    short8 bh = *(const short8*)&img_hi[p][32 * kt + 8 * g];
                    short8 bl = *(const short8*)&img_lo[p][32 * kt + 8 * g];
                    #pragma unroll
                    for (int t = 0; t < 4; ++t) {
                        accA[t] = __builtin_amdgcn_mfma_f32_16x16x32_bf16(waH[t][kt], bh, accA[t], 0, 0, 0);
                        accB[t] = __builtin_amdgcn_mfma_f32_16x16x32_bf16(waH[t][kt], bl, accB[t], 0, 0, 0);
                        accC[t] = __builtin_amdgcn_mfma_f32_16x16x32_bf16(waL[t][kt], bh, accC[t], 0, 0, 0);
                    }
                }
                if (col == 0) {   // D col 0: rows (lane>>4)*4 + j of each row-tile
                    #pragma unroll
                    for (int t = 0; t < 4; ++t) {
                        f4 d = accA[t] + accB[t] + accC[t];
                        const int m0 = 16 * (4 * wv + t) + 4 * g;
                        f4 a4 = *(const f4*)&apL[s][m0];
                        f4 h4;
                        #pragma unroll
                        for (int jj = 0; jj < 4; ++jj) h4[jj] = tanh_fast(d[jj] + a4[jj]);
                        if (l < NLAY - 1)
                            st_coh_f4(Hout + (size_t)((k & 7) * CHUNK + s) * HID + m0, h4);
                        else if (k == NCHUNK - 1 && s == CHUNK - 1)
                            st_coh_f4(hfin + m0, h4);
                        u16x4 hh, ll;
                        #pragma unroll
                        for (int jj = 0; jj < 4; ++jj) {
                            unsigned short x_ = bf_hi(h4[jj]);
                            hh[jj] = x_;
                            ll[jj] = bf_hi(h4[jj] - bf2f(x_));
                        }
                        *(u16x4*)&img_hi[p ^ 1][m0] = hh;
                        *(u16x4*)&img_lo[p ^ 1][m0] = ll;
                    }
                }
                if (s == 2 && havePF) {
                    if (l0) {
                        #pragma unroll
                        for (int s2 = 0; s2 < CHUNK; ++s2)
                            apn[s2] = Psrc[(size_t)(CHUNK * (k + 1) + s2) * HID + m];
                    } else {
                        #pragma unroll
                        for (int s2 = 0; s2 < CHUNK; ++s2)
                            apn[s2] = ld_coh_b32(apbuf + (size_t)(((k + 1) & 7) * CHUNK + s2) * HID + m);
                    }
                }
                LGKM0(); SBAR();
            }
            // ---------- drain + publish ----------
            VMW0(); SBAR();
            if (tid == 0) st_coh_u32(myHfl, (unsigned)(k + 1));
        }
    } else {
        // ===================== A role (l = 1..15) =====================
        const float*    Hin    = Hring + ((size_t)(c * NLAY + (l - 1)) * QS) * HID;
        const unsigned* inflag = Hflag + c * NLAY + (l - 1);
        float*          Aout   = Apart + ((size_t)(c * NLAY + l) * QS) * HID;
        unsigned*       myAfl  = Aflag + c * NLAY + l;
        const unsigned* consB  = Hflag + c * NLAY + l;

        float h8[CHUNK], h8n[CHUNK];
        bool havePF = false, bpok = true;

        for (int k = 0; k < NCHUNK; ++k) {
            // ---------- chunk top ----------
            if (lane == 0) {
                if (!havePF) spin_ge(inflag, (unsigned)(k + 1), &dead);
                if (k >= CHUNK && !bpok) spin_ge(consB, (unsigned)(k - 7), &dead);
            }
            unsigned inv = 0u, bpv = 0u;
            const bool pollIn = (k + 1 < NCHUNK);
            const bool pollBp = (k + 1 >= CHUNK) && (k + 1 < NCHUNK);
            if (lane == 0 && pollIn)
                asm volatile("global_load_dword %0, %1, off sc0 sc1" : "=v"(inv) : "v"(inflag));
            if (lane == 0 && pollBp)
                asm volatile("global_load_dword %0, %1, off sc0 sc1" : "=v"(bpv) : "v"(consB));

            if (havePF) {
                VMW0();
                #pragma unroll
                for (int s = 0; s < CHUNK; ++s) h8[s] = h8n[s];
            } else {
                #pragma unroll
                for (int s = 0; s < CHUNK; ++s)
                    h8[s] = ld_coh_b32(Hin + (size_t)((k & 7) * CHUNK + s) * HID + m);
                VMW0();
            }
            {
                unsigned ins = (unsigned)__builtin_amdgcn_readfirstlane((int)inv);
                unsigned bps = (unsigned)__builtin_amdgcn_readfirstlane((int)bpv);
                havePF = pollIn && (ins >= (unsigned)(k + 2));
                bpok   = pollBp ? (bps >= (unsigned)(k - 6)) : true;
            }
            // stage bf16 hi/lo images for the chunk
            #pragma unroll
            for (int s = 0; s < CHUNK; ++s) {
                unsigned short x_ = bf_hi(h8[s]);
                stgH[s][m] = x_;
                stgL[s][m] = bf_hi(h8[s] - bf2f(x_));
            }
            LGKM0(); SBAR();

            // ---------- 8 steps, no per-step barriers ----------
            for (int s = 0; s < CHUNK; ++s) {
                f4 accA[4], accB[4], accC[4];
                #pragma unroll
                for (int t = 0; t < 4; ++t) { accA[t] = (f4)0.f; accB[t] = (f4)0.f; accC[t] = (f4)0.f; }
                #pragma unroll
                for (int kt = 0; kt < 8; ++kt) {
                    short8 bh = *(const short8*)&stgH[s][32 * kt + 8 * g];
                    short8 bl = *(const short8*)&stgL[s][32 * kt + 8 * g];
                    #pragma unroll
                    for (int t = 0; t < 4; ++t) {
                        accA[t] = __builtin_amdgcn_mfma_f32_16x16x32_bf16(waH[t][kt], bh, accA[t], 0, 0, 0);
                        accB[t] = __builtin_amdgcn_mfma_f32_16x16x32_bf16(waH[t][kt], bl, accB[t], 0, 0, 0);
                        accC[t] = __builtin_amdgcn_mfma_f32_16x16x32_bf16(waL[t][kt], bh, accC[t], 0, 0, 0);
                    }
                }
                if (col == 0) {
                    #pragma unroll
                    for (int t = 0; t < 4; ++t) {
                        f4 d = accA[t] + accB[t] + accC[t];
                        const int m0 = 16 * (4 * wv + t) + 4 * g;
                        st_coh_f4(Aout + (size_t)((k & 7) * CHUNK + s) * HID + m0, d);
                    }
                }
                if (s == 2 && havePF) {
                    #pragma unroll
                    for (int s2 = 0; s2 < CHUNK; ++s2)
                        h8n[s2] = ld_coh_b32(Hin + (size_t)(((k + 1) & 7) * CHUNK + s2) * HID + m);
                }
            }
            // ---------- drain + publish ----------
            VMW0(); SBAR();
            if (tid == 0) st_coh_u32(myAfl, (unsigned)(k + 1));
        }
    }
}

// ---------------------------------------------------------------------------
// Kernel 3: out = fc_W @ concat(h0..h3) + fc_b
__global__ __launch_bounds__(1024) void fc_kernel(
    const float* __restrict__ hfinal, const float* __restrict__ fcW,
    const float* __restrict__ fcb, float* __restrict__ out)
{
    __shared__ float red[1024];
    const int tid = threadIdx.x;
    float v  = hfinal[tid];
    float p0 = fcW[tid] * v;
    float p1 = fcW[1024 + tid] * v;

    red[tid] = p0; __syncthreads();
    for (int st = 512; st > 0; st >>= 1) { if (tid < st) red[tid] += red[tid + st]; __syncthreads(); }
    if (tid == 0) out[0] = red[0] + fcb[0];
    __syncthreads();
    red[tid] = p1; __syncthreads();
    for (int st = 512; st > 0; st >>= 1) { if (tid < st) red[tid] += red[tid + st]; __syncthreads(); }
    if (tid == 0) out[1] = red[0] + fcb[1];
}

// ---------------------------------------------------------------------------
extern "C" void kernel_launch(void* const* d_in, const int* in_sizes, int n_in,
                              void* d_out, int out_size, void* d_ws, size_t ws_size,
                              hipStream_t stream)
{
    (void)in_sizes; (void)n_in; (void)out_size; (void)ws_size;
    const float* x        = (const float*)d_in[0];
    const float* lp_Wih0  = (const float*)d_in[1];
    const float* lp_Wih   = (const float*)d_in[2];
    const float* lp_Whh   = (const float*)d_in[3];
    const float* lp_bih   = (const float*)d_in[4];
    const float* lp_bhh   = (const float*)d_in[5];
    const float* lpv_Wih0 = (const float*)d_in[6];
    const float* lpv_Wih  = (const float*)d_in[7];
    const float* lpv_Whh  = (const float*)d_in[8];
    const float* lpv_bih  = (const float*)d_in[9];
    const float* lpv_bhh  = (const float*)d_in[10];
    const float* fcW      = (const float*)d_in[11];
    const float* fcb      = (const float*)d_in[12];

    float* ws      = (float*)d_ws;
    float* Pbuf    = ws + P_OFF;
    float* Hring   = ws + H_OFF;
    float* Apart   = ws + AP_OFF;
    float* hfinal  = ws + HF_OFF;
    unsigned* flags = (unsigned*)(ws + FLAG_OFF_FLOATS);

    hipMemsetAsync(flags, 0, NFLAGS * sizeof(unsigned), stream);

    proj_kernel<<<SEQL / TPB, 1024, 0, stream>>>(x, lp_Wih0, lpv_Wih0, Pbuf);

    rnn_pipe<<<124, 256, 0, stream>>>(lp_Wih, lp_Whh, lp_bih, lp_bhh,
                                      lpv_Wih, lpv_Whh, lpv_bih, lpv_bhh,
                                      Pbuf, Hring, Apart, hfinal,
                                      flags, flags + 64);

    fc_kernel<<<1, 1024, 0, stream>>>(hfinal, fcW, fcb, (float*)d_out);
}

// Round 17
// 6202.057 us; speedup vs baseline: 1.8859x; 1.8859x over previous
//
#include <hip/hip_runtime.h>
#include <hip/hip_bf16.h>
#include <math.h>

#define SEQL   4096
#define NITEMS 512
#define HID    256
#define NLAY   16
#define QS     64      // ring slots = 8 chunks x 8 steps
#define CHUNK  8
#define NCHUNK (SEQL / CHUNK)
#define TPB    4

typedef float f4 __attribute__((ext_vector_type(4)));
typedef short short8 __attribute__((ext_vector_type(8)));
typedef unsigned short u16x4 __attribute__((ext_vector_type(4)));

// Workspace layout (float offsets)
#define P_OFF   ((size_t)0)                               // P[4][SEQL][HID]
#define H_OFF   (P_OFF + (size_t)4*SEQL*HID)              // Hring[4][NLAY][QS][HID]
#define AP_OFF  (H_OFF + (size_t)4*NLAY*QS*HID)           // Apart[4][NLAY][QS][HID]
#define HF_OFF  (AP_OFF + (size_t)4*NLAY*QS*HID)          // hfinal[4][HID]
#define FLAG_OFF_FLOATS (HF_OFF + (size_t)1024)
#define NFLAGS 256

// ---------------------------------------------------------------------------
__device__ __forceinline__ float ld_coh_b32(const float* p) {
    float r;
    asm volatile("global_load_dword %0, %1, off sc0 sc1" : "=v"(r) : "v"(p));
    return r;
}
__device__ __forceinline__ void st_coh_f4(float* p, f4 v) {
    asm volatile("global_store_dwordx4 %0, %1, off sc0 sc1" :: "v"(p), "v"(v) : "memory");
}
__device__ __forceinline__ void st_coh_u32(unsigned* p, unsigned v) {
    asm volatile("global_store_dword %0, %1, off sc0 sc1" :: "v"(p), "v"(v) : "memory");
}
__device__ __forceinline__ unsigned uload(const unsigned* p) {
    return __hip_atomic_load(p, __ATOMIC_RELAXED, __HIP_MEMORY_SCOPE_AGENT);
}

#define SBAR()  { __builtin_amdgcn_s_barrier(); __builtin_amdgcn_sched_barrier(0); }
#define LGKM0() { asm volatile("s_waitcnt lgkmcnt(0)" ::: "memory"); __builtin_amdgcn_sched_barrier(0); }
#define VMW0()  { asm volatile("s_waitcnt vmcnt(0)" ::: "memory"); __builtin_amdgcn_sched_barrier(0); }
#define WAIT_PIN(reg) { asm volatile("s_waitcnt vmcnt(0)" : "+v"(reg) :: "memory"); \
                        __builtin_amdgcn_sched_barrier(0); }

__device__ __forceinline__ void spin_ge(const unsigned* p, unsigned target, bool* dead) {
    if (*dead) return;
    unsigned it = 0;
    while (uload(p) < target) {
        __builtin_amdgcn_s_sleep(1);
        if (++it > (1u << 20)) { *dead = true; break; }
    }
}

__device__ __forceinline__ float tanh_fast(float x) {
    return 1.f - __fdividef(2.f, __expf(2.f * x) + 1.f);
}

// bf16 split helpers (RNE)
__device__ __forceinline__ unsigned short bf_hi(float f) {
    unsigned u = __float_as_uint(f);
    return (unsigned short)((u + 0x7FFFu + ((u >> 16) & 1u)) >> 16);
}
__device__ __forceinline__ float bf2f(unsigned short s) {
    return __uint_as_float(((unsigned)s) << 16);
}

// o = ror8(a) + b  (within 16-lane rows; lane q reads lane (q-8)&15 — R10-verified)
__device__ __forceinline__ float dpp_ror8_add(float a, float b) {
    float o;
    asm volatile("v_add_f32_dpp %0, %1, %2 row_ror:8 row_mask:0xf bank_mask:0xf"
                 : "=&v"(o) : "v"(a), "v"(b));
    return o;
}

// ---------------------------------------------------------------------------
// Kernel 1: input projection P[c][t][j] = sum_k Wih0_c[j,k] * x[t,k,c]
__global__ __launch_bounds__(1024) void proj_kernel(
    const float* __restrict__ x, const float* __restrict__ Wlp,
    const float* __restrict__ Wlpv, float* __restrict__ P)
{
    __shared__ float xs[TPB][4][NITEMS];
    const int tid = threadIdx.x;
    const int t0 = blockIdx.x * TPB;

    #pragma unroll
    for (int tt = 0; tt < TPB; ++tt) {
        const float2* src = (const float2*)(x + (size_t)(t0 + tt) * NITEMS * 4);
        float2 v = src[tid];
        int e = 2 * tid;
        xs[tt][e & 3][e >> 2]       = v.x;
        xs[tt][(e + 1) & 3][e >> 2] = v.y;
    }
    __syncthreads();

    const int c = tid >> 8, j = tid & 255;
    const float* W = (c == 1) ? Wlpv : Wlp;
    const float4* row = (const float4*)(W + (size_t)j * NITEMS);
    float acc[TPB] = {0.f, 0.f, 0.f, 0.f};
    #pragma unroll 4
    for (int k4 = 0; k4 < NITEMS / 4; ++k4) {
        float4 w = row[k4];
        #pragma unroll
        for (int tt = 0; tt < TPB; ++tt) {
            float4 xv = *(const float4*)(&xs[tt][c][k4 * 4]);
            acc[tt] = fmaf(w.x, xv.x, fmaf(w.y, xv.y, fmaf(w.z, xv.z, fmaf(w.w, xv.w, acc[tt]))));
        }
    }
    #pragma unroll
    for (int tt = 0; tt < TPB; ++tt)
        P[((size_t)c * SEQL + (t0 + tt)) * HID + j] = acc[tt];
}

// ---------------------------------------------------------------------------
// Kernel 2: layer-pipelined RNN. R12 protocol, MFMA core with column-packed
// hi|lo (B cols 0-7 = h_hi, 8-15 = h_lo => 4-term split in 2 MFMA/kt).
// 1024 threads = 16 waves; wave RT owns rows 16RT..16RT+15 (64 VGPR weights).
__global__ __launch_bounds__(1024, 1) void rnn_pipe(
    const float* __restrict__ lp_Wih,  const float* __restrict__ lp_Whh,
    const float* __restrict__ lp_bih,  const float* __restrict__ lp_bhh,
    const float* __restrict__ lpv_Wih, const float* __restrict__ lpv_Whh,
    const float* __restrict__ lpv_bih, const float* __restrict__ lpv_bhh,
    const float* __restrict__ P, float* __restrict__ Hring,
    float* __restrict__ Apart, float* __restrict__ hfinal,
    unsigned* __restrict__ Hflag, unsigned* __restrict__ Aflag)
{
    __shared__ __align__(16) unsigned short img_hi[2][HID], img_lo[2][HID]; // B: h images
    __shared__ __align__(16) unsigned short stgH[CHUNK][HID], stgL[CHUNK][HID]; // A: staged h
    __shared__ __align__(16) float apL[CHUNK][HID];                         // B: inputs(+bias)
    __shared__ int pf_lds[2];

    const int b = blockIdx.x;
    if (b >= 124) return;
    const int tid = threadIdx.x;

    const int c = b / 31;
    const int r = b % 31;
    const int role = (r < NLAY) ? 0 : 1;
    const int l = (r < NLAY) ? r : (r - NLAY + 1);

    const float* Wih = (c == 1) ? lpv_Wih : lp_Wih;
    const float* Whh = (c == 1) ? lpv_Whh : lp_Whh;
    const float* bih = (c == 1) ? lpv_bih : lp_bih;
    const float* bhh = (c == 1) ? lpv_bhh : lp_bhh;

    const int RT   = tid >> 6;        // wave = row-tile 0..15
    const int lane = tid & 63;
    const int g    = lane >> 4;       // k-subgroup / D-row group
    const int col  = lane & 15;       // A row-in-tile / D col
    const int m2   = tid & 255;       // staging column
    const int sA   = tid >> 8;        // staging timestep (and sA+4)
    bool dead = false;

    // ---- weights: wave RT rows 16RT+col, k = 32kt + 8g + j (layout verified R16) ----
    short8 waH[8], waL[8];
    {
        const float* Wb = (role == 0) ? (Whh + (size_t)l * HID * HID)
                                      : (Wih + (size_t)(l - 1) * HID * HID);
        const float* prow = Wb + (size_t)(16 * RT + col) * HID + 8 * g;
        #pragma unroll
        for (int kt = 0; kt < 8; ++kt) {
            f4 v0 = *(const f4*)(prow + 32 * kt);
            f4 v1 = *(const f4*)(prow + 32 * kt + 4);
            float vv[8] = {v0.x, v0.y, v0.z, v0.w, v1.x, v1.y, v1.z, v1.w};
            short8 hi8, lo8;
            #pragma unroll
            for (int jj = 0; jj < 8; ++jj) {
                unsigned short h_ = bf_hi(vv[jj]);
                hi8[jj] = (short)h_;
                lo8[jj] = (short)bf_hi(vv[jj] - bf2f(h_));
            }
            waH[kt] = hi8; waL[kt] = lo8;
        }
    }
    #pragma unroll
    for (int kt = 0; kt < 8; ++kt) asm volatile("" : "+v"(waH[kt]), "+v"(waL[kt]));

    const int m0 = 16 * RT + 4 * g;   // tail rows (active lanes col==0 / n<8)

    if (role == 0) {
        // ===================== B role =====================
        const bool l0 = (l == 0);
        const float*    Psrc  = P + (size_t)c * SEQL * HID;
        const float*    apbuf = Apart + ((size_t)(c * NLAY + l) * QS) * HID;
        const unsigned* af    = Aflag + c * NLAY + l;
        unsigned*       myHfl = Hflag + c * NLAY + l;
        const unsigned* consA = Aflag + c * NLAY + l + 1;   // valid when l<15
        float*          Hout  = Hring + ((size_t)(c * NLAY + l) * QS) * HID;
        float*          hfin  = hfinal + (size_t)c * HID;
        const float bias_m2 = bih[l * HID + m2] + bhh[l * HID + m2];

        // init h(-1)=0 image
        if (tid < 256) { img_hi[0][tid] = 0; img_lo[0][tid] = 0; }
        LGKM0(); SBAR();

        float apn0 = 0.f, apn1 = 0.f;
        bool havePF = false;

        for (int k = 0; k < NCHUNK; ++k) {
            // ---------- chunk top ----------
            int pf2ok = 1;
            if (k >= CHUNK && l < NLAY - 1) pf2ok = pf_lds[1];
            const bool needbar = (!havePF && !l0) || !pf2ok;
            if (needbar) {
                if (tid == 0) {
                    if (!havePF && !l0) spin_ge(af, (unsigned)(k + 1), &dead);
                    if (!pf2ok) spin_ge(consA, (unsigned)(k - 7), &dead);
                }
                SBAR();
            }
            // stage 2 values/thread into apL (with bias folded)
            if (havePF) {
                VMW0();
                apL[sA][m2]     = apn0 + bias_m2;
                apL[sA + 4][m2] = apn1 + bias_m2;
            } else {
                float a0, a1;
                if (l0) {
                    a0 = Psrc[(size_t)(CHUNK * k + sA) * HID + m2];
                    a1 = Psrc[(size_t)(CHUNK * k + sA + 4) * HID + m2];
                } else {
                    a0 = ld_coh_b32(apbuf + (size_t)((k & 7) * CHUNK + sA) * HID + m2);
                    a1 = ld_coh_b32(apbuf + (size_t)((k & 7) * CHUNK + sA + 4) * HID + m2);
                }
                VMW0();
                apL[sA][m2]     = a0 + bias_m2;
                apL[sA + 4][m2] = a1 + bias_m2;
            }
            // polls (checked at s==1)
            unsigned afv = 0u, bpv = 0u;
            const bool pollIn = (!l0) && (k + 1 < NCHUNK);
            const bool pollBp = (l < NLAY - 1) && (k + 1 >= CHUNK) && (k + 1 < NCHUNK);
            if (tid == 64 && pollIn)
                asm volatile("global_load_dword %0, %1, off sc0 sc1" : "=v"(afv) : "v"(af));
            if (tid == 65 && pollBp)
                asm volatile("global_load_dword %0, %1, off sc0 sc1" : "=v"(bpv) : "v"(consA));
            LGKM0(); SBAR();

            // ---------- 8 inner steps, one barrier each ----------
            for (int s = 0; s < CHUNK; ++s) {
                const int p = s & 1;
                const unsigned short* bsrc = (lane & 8) ? &img_lo[p][0] : &img_hi[p][0];
                f4 accA = (f4)0.f, accD = (f4)0.f;
                #pragma unroll
                for (int kt = 0; kt < 8; ++kt) {
                    short8 bf = *(const short8*)&bsrc[32 * kt + 8 * g];
                    accA = __builtin_amdgcn_mfma_f32_16x16x32_bf16(waH[kt], bf, accA, 0, 0, 0);
                    accD = __builtin_amdgcn_mfma_f32_16x16x32_bf16(waL[kt], bf, accD, 0, 0, 0);
                }
                f4 dtot = accA + accD;
                f4 dsum;
                #pragma unroll
                for (int jj = 0; jj < 4; ++jj) dsum[jj] = dpp_ror8_add(dtot[jj], dtot[jj]);
                if (col == 0) {
                    f4 a4 = *(const f4*)&apL[s][m0];
                    f4 h4;
                    #pragma unroll
                    for (int jj = 0; jj < 4; ++jj) h4[jj] = tanh_fast(dsum[jj] + a4[jj]);
                    u16x4 hh, ll;
                    #pragma unroll
                    for (int jj = 0; jj < 4; ++jj) {
                        unsigned short x_ = bf_hi(h4[jj]);
                        hh[jj] = x_;
                        ll[jj] = bf_hi(h4[jj] - bf2f(x_));
                    }
                    *(u16x4*)&img_hi[p ^ 1][m0] = hh;
                    *(u16x4*)&img_lo[p ^ 1][m0] = ll;
                    if (l < NLAY - 1)
                        st_coh_f4(Hout + (size_t)((k & 7) * CHUNK + s) * HID + m0, h4);
                    else if (k == NCHUNK - 1 && s == CHUNK - 1)
                        st_coh_f4(hfin + m0, h4);
                }
                if (s == 1) {
                    if (tid == 64 && pollIn) { WAIT_PIN(afv); pf_lds[0] = (afv >= (unsigned)(k + 2)); }
                    if (tid == 65 && pollBp) { WAIT_PIN(bpv); pf_lds[1] = (bpv >= (unsigned)(k - 6)); }
                }
                if (s == 2) {
                    havePF = false;
                    if (k + 1 < NCHUNK) {
                        const bool b1 = l0 || (pf_lds[0] != 0);
                        if (b1) {
                            havePF = true;
                            if (l0) {
                                apn0 = Psrc[(size_t)(CHUNK * (k + 1) + sA) * HID + m2];
                                apn1 = Psrc[(size_t)(CHUNK * (k + 1) + sA + 4) * HID + m2];
                            } else {
                                apn0 = ld_coh_b32(apbuf + (size_t)(((k + 1) & 7) * CHUNK + sA) * HID + m2);
                                apn1 = ld_coh_b32(apbuf + (size_t)(((k + 1) & 7) * CHUNK + sA + 4) * HID + m2);
                            }
                        }
                    }
                }
                LGKM0(); SBAR();
            }
            // ---------- drain + publish ----------
            VMW0(); SBAR();
            if (tid == 0) st_coh_u32(myHfl, (unsigned)(k + 1));
        }
    } else {
        // ===================== A role (l = 1..15): 8 timesteps per MFMA batch ==
        const float*    Hin    = Hring + ((size_t)(c * NLAY + (l - 1)) * QS) * HID;
        const unsigned* inflag = Hflag + c * NLAY + (l - 1);
        float*          Aout   = Apart + ((size_t)(c * NLAY + l) * QS) * HID;
        unsigned*       myAfl  = Aflag + c * NLAY + l;
        const unsigned* consB  = Hflag + c * NLAY + l;

        float hn0 = 0.f, hn1 = 0.f;
        bool havePF = false;

        for (int k = 0; k < NCHUNK; ++k) {
            // ---------- chunk top ----------
            int pf2ok = 1;
            if (k >= CHUNK) pf2ok = pf_lds[1];
            const bool needbar = !havePF || !pf2ok;
            if (needbar) {
                if (tid == 0) {
                    if (!havePF) spin_ge(inflag, (unsigned)(k + 1), &dead);
                    if (!pf2ok)  spin_ge(consB, (unsigned)(k - 7), &dead);
                }
                SBAR();
            }
            float h0, h1;
            if (havePF) {
                VMW0();
                h0 = hn0; h1 = hn1;
            } else {
                h0 = ld_coh_b32(Hin + (size_t)((k & 7) * CHUNK + sA) * HID + m2);
                h1 = ld_coh_b32(Hin + (size_t)((k & 7) * CHUNK + sA + 4) * HID + m2);
                VMW0();
            }
            {
                unsigned short x0 = bf_hi(h0), x1 = bf_hi(h1);
                stgH[sA][m2] = x0;     stgL[sA][m2] = bf_hi(h0 - bf2f(x0));
                stgH[sA + 4][m2] = x1; stgL[sA + 4][m2] = bf_hi(h1 - bf2f(x1));
            }
            unsigned inv = 0u, bpv = 0u;
            const bool pollIn = (k + 1 < NCHUNK);
            const bool pollBp = (k + 1 >= CHUNK) && (k + 1 < NCHUNK);
            if (tid == 64 && pollIn)
                asm volatile("global_load_dword %0, %1, off sc0 sc1" : "=v"(inv) : "v"(inflag));
            if (tid == 65 && pollBp)
                asm volatile("global_load_dword %0, %1, off sc0 sc1" : "=v"(bpv) : "v"(consB));
            LGKM0(); SBAR();

            // ---------- one MFMA batch covers all 8 timesteps ----------
            {
                const int ts = col & 7;   // timestep this column serves
                const unsigned short* bsrc = (lane & 8) ? &stgL[ts][0] : &stgH[ts][0];
                f4 accA = (f4)0.f, accD = (f4)0.f;
                #pragma unroll
                for (int kt = 0; kt < 8; ++kt) {
                    short8 bf = *(const short8*)&bsrc[32 * kt + 8 * g];
                    accA = __builtin_amdgcn_mfma_f32_16x16x32_bf16(waH[kt], bf, accA, 0, 0, 0);
                    accD = __builtin_amdgcn_mfma_f32_16x16x32_bf16(waL[kt], bf, accD, 0, 0, 0);
                }
                f4 dtot = accA + accD;
                f4 dsum;
                #pragma unroll
                for (int jj = 0; jj < 4; ++jj) dsum[jj] = dpp_ror8_add(dtot[jj], dtot[jj]);
                if (!(lane & 8))   // cols 0-7 hold the full 4-term sum for timestep ts
                    st_coh_f4(Aout + (size_t)((k & 7) * CHUNK + ts) * HID + m0, dsum);
            }
            // ---------- polls, drain, publish, prefetch ----------
            if (tid == 64 && pollIn) { WAIT_PIN(inv); pf_lds[0] = (inv >= (unsigned)(k + 2)); }
            if (tid == 65 && pollBp) { WAIT_PIN(bpv); pf_lds[1] = (bpv >= (unsigned)(k - 6)); }
            VMW0(); LGKM0(); SBAR();
            havePF = false;
            if (k + 1 < NCHUNK && pf_lds[0] != 0) {
                havePF = true;
                hn0 = ld_coh_b32(Hin + (size_t)(((k + 1) & 7) * CHUNK + sA) * HID + m2);
                hn1 = ld_coh_b32(Hin + (size_t)(((k + 1) & 7) * CHUNK + sA + 4) * HID + m2);
            }
            if (tid == 0) st_coh_u32(myAfl, (unsigned)(k + 1));
        }
    }
}

// ---------------------------------------------------------------------------
// Kernel 3: out = fc_W @ concat(h0..h3) + fc_b
__global__ __launch_bounds__(1024) void fc_kernel(
    const float* __restrict__ hfinal, const float* __restrict__ fcW,
    const float* __restrict__ fcb, float* __restrict__ out)
{
    __shared__ float red[1024];
    const int tid = threadIdx.x;
    float v  = hfinal[tid];
    float p0 = fcW[tid] * v;
    float p1 = fcW[1024 + tid] * v;

    red[tid] = p0; __syncthreads();
    for (int st = 512; st > 0; st >>= 1) { if (tid < st) red[tid] += red[tid + st]; __syncthreads(); }
    if (tid == 0) out[0] = red[0] + fcb[0];
    __syncthreads();
    red[tid] = p1; __syncthreads();
    for (int st = 512; st > 0; st >>= 1) { if (tid < st) red[tid] += red[tid + st]; __syncthreads(); }
    if (tid == 0) out[1] = red[0] + fcb[1];
}

// ---------------------------------------------------------------------------
extern "C" void kernel_launch(void* const* d_in, const int* in_sizes, int n_in,
                              void* d_out, int out_size, void* d_ws, size_t ws_size,
                              hipStream_t stream)
{
    (void)in_sizes; (void)n_in; (void)out_size; (void)ws_size;
    const float* x        = (const float*)d_in[0];
    const float* lp_Wih0  = (const float*)d_in[1];
    const float* lp_Wih   = (const float*)d_in[2];
    const float* lp_Whh   = (const float*)d_in[3];
    const float* lp_bih   = (const float*)d_in[4];
    const float* lp_bhh   = (const float*)d_in[5];
    const float* lpv_Wih0 = (const float*)d_in[6];
    const float* lpv_Wih  = (const float*)d_in[7];
    const float* lpv_Whh  = (const float*)d_in[8];
    const float* lpv_bih  = (const float*)d_in[9];
    const float* lpv_bhh  = (const float*)d_in[10];
    const float* fcW      = (const float*)d_in[11];
    const float* fcb      = (const float*)d_in[12];

    float* ws      = (float*)d_ws;
    float* Pbuf    = ws + P_OFF;
    float* Hring   = ws + H_OFF;
    float* Apart   = ws + AP_OFF;
    float* hfinal  = ws + HF_OFF;
    unsigned* flags = (unsigned*)(ws + FLAG_OFF_FLOATS);

    hipMemsetAsync(flags, 0, NFLAGS * sizeof(unsigned), stream);

    proj_kernel<<<SEQL / TPB, 1024, 0, stream>>>(x, lp_Wih0, lpv_Wih0, Pbuf);

    rnn_pipe<<<124, 1024, 0, stream>>>(lp_Wih, lp_Whh, lp_bih, lp_bhh,
                                       lpv_Wih, lpv_Whh, lpv_bih, lpv_bhh,
                                       Pbuf, Hring, Apart, hfinal,
                                       flags, flags + 64);

    fc_kernel<<<1, 1024, 0, stream>>>(hfinal, fcW, fcb, (float*)d_out);
}